// Round 9
// baseline (226.681 us; speedup 1.0000x reference)
//
#include <hip/hip_runtime.h>
#include <hip/hip_cooperative_groups.h>

namespace cg = cooperative_groups;

typedef __attribute__((ext_vector_type(8))) short bf16x8;
typedef __attribute__((ext_vector_type(4))) float f32x4;
typedef __attribute__((ext_vector_type(4))) unsigned int u32x4;

#define TT 4096
#define DD 64
#define NCH2 128
#define CS2 32   // TT / NCH2

// ws layout (in floats)
#define Q_OFF    0
#define K_OFF    (TT*DD)                    // 262144
#define Z_OFF    (K_OFF + 4*TT*DD)          // 1310720
#define CSUM_OFF (Z_OFF + 8*TT*DD)          // 3407872  (8*NCH2*DD = 65536)
#define T_OFF    (CSUM_OFF + 8*NCH2*DD)     // 3473408  (4*TT = 16384) ~13.9 MB

// ---------------------------------------------------------------------------
// ONE cooperative kernel, three phases separated by device-fenced grid syncs.
// Grid = 320 blocks x 256 threads (4 waves). Co-residency: 2 blocks/CU max
// needed (LDS ~20KB, <=8 waves/CU) -> far inside cooperative capacity.
//
// Phase A (blocks = 5 mlps x 64 row-tiles): MFMA MLP exactly as r8 (split-
// bf16, hh+hl+lh), but W fragments are converted in-register straight from
// the fp32 weights (wpack kernel eliminated). Fused 32-row csums + V/t
// extraction. Wave w owns rows [16w,16w+16) = one 16x16x32 M-tile.
// Phase B: zfill verbatim r8 — wave_id = blockIdx*4+w covers 1024 tasks.
// Phase C: gather verbatim r3, wave-strided over the 4096 output rows.
// ---------------------------------------------------------------------------
__global__ __launch_bounds__(256) void fused_kernel(
    const float* __restrict__ x1, const float* __restrict__ x2,
    const float* __restrict__ x3, const float* __restrict__ x4,
    const float* __restrict__ Wq_w, const float* __restrict__ Wq_b,
    const float* __restrict__ Wk_w, const float* __restrict__ Wk_b,
    float* __restrict__ ws, float* __restrict__ out)
{
    const int tid = threadIdx.x;
    const int l   = tid & 63;
    const int w   = tid >> 6;
    const int b   = blockIdx.x;        // 0..319
    cg::grid_group grid = cg::this_grid();

    // ---------------- Phase A: MLP via MFMA + csum ----------------
    {
        const int q  = b >> 6;         // 0 = Q-mlp, 1..4 = K-mlp (m=q-1)
        const int br = b & 63;         // 64-row tile

        const float* x; const float* Wsrc; const float* Bsrc; float* o;
        if (q == 0) { x = x1; Wsrc = Wq_w; Bsrc = Wq_b; o = ws + Q_OFF; }
        else {
            const int m = q - 1;
            x = (m == 0) ? x1 : (m == 1) ? x2 : (m == 2) ? x3 : x4;
            Wsrc = Wk_w + m * 3 * DD * DD;
            Bsrc = Wk_b + m * 3 * DD;
            o = ws + K_OFF + m * TT * DD;
        }

        __shared__ float hs[64 * 68];
        __shared__ float vb[2 * 64];
        __shared__ float ps[4][2][64];

        // coalesced tile load: 64x64 = 1024 float4 over 256 threads
        {
            const float4* xv = reinterpret_cast<const float4*>(x + br * 64 * DD);
            #pragma unroll
            for (int i = 0; i < 4; ++i) {
                const int idx = tid + i * 256;
                const float4 v = xv[idx];
                const int e = idx * 4;
                const int row = e >> 6, k0 = e & 63;
                *reinterpret_cast<float4*>(&hs[row * 68 + k0]) = v;
                if (k0 == 0) { vb[row] = v.x; vb[DD + row] = v.y; }
                if (q >= 1 && k0 == 60) ws[T_OFF + (q - 1) * TT + br * 64 + row] = v.w;
            }
        }
        __syncthreads();

        const int lane15 = l & 15, lhi = l >> 4;
        const int wrow = w * 16;

        for (int L = 0; L < 3; ++L) {
            f32x4 acc[4];
            #pragma unroll
            for (int n = 0; n < 4; ++n) acc[n] = (f32x4){0.f, 0.f, 0.f, 0.f};

            #pragma unroll
            for (int t = 0; t < 2; ++t) {
                // B fragments for this t: convert from fp32 W in-register.
                // lane l supplies W[t*32+lhi*8+j][n*16+lane15], j=0..7.
                bf16x8 bh[4], bl[4];
                #pragma unroll
                for (int n = 0; n < 4; ++n) {
                    const float* wp0 = Wsrc + L * DD * DD
                                     + (t * 32 + lhi * 8) * DD + n * 16 + lane15;
                    unsigned int hw[4], lw[4];
                    #pragma unroll
                    for (int p = 0; p < 4; ++p) {
                        const float w0 = wp0[(2 * p) * DD];
                        const float w1 = wp0[(2 * p + 1) * DD];
                        const unsigned int u0 = __float_as_uint(w0) >> 16;
                        const unsigned int u1 = __float_as_uint(w1) >> 16;
                        const float f0 = w0 - __uint_as_float(u0 << 16);
                        const float f1 = w1 - __uint_as_float(u1 << 16);
                        const unsigned int v0 = __float_as_uint(f0);
                        const unsigned int v1 = __float_as_uint(f1);
                        const unsigned int l0 = (v0 + 0x7FFFu + ((v0 >> 16) & 1u)) >> 16;
                        const unsigned int l1 = (v1 + 0x7FFFu + ((v1 >> 16) & 1u)) >> 16;
                        hw[p] = u0 | (u1 << 16);
                        lw[p] = l0 | (l1 << 16);
                    }
                    bh[n] = __builtin_bit_cast(bf16x8, (u32x4){hw[0], hw[1], hw[2], hw[3]});
                    bl[n] = __builtin_bit_cast(bf16x8, (u32x4){lw[0], lw[1], lw[2], lw[3]});
                }

                // A fragment for this t from LDS + split conversion
                bf16x8 ah, al;
                {
                    const float* src = &hs[(wrow + lane15) * 68 + t * 32 + lhi * 8];
                    float x8[8];
                    *reinterpret_cast<float4*>(&x8[0]) = *reinterpret_cast<const float4*>(src);
                    *reinterpret_cast<float4*>(&x8[4]) = *reinterpret_cast<const float4*>(src + 4);
                    unsigned int hw[4], lw[4];
                    #pragma unroll
                    for (int p = 0; p < 4; ++p) {
                        const unsigned int u0 = __float_as_uint(x8[2 * p]) >> 16;
                        const unsigned int u1 = __float_as_uint(x8[2 * p + 1]) >> 16;
                        const float f0 = x8[2 * p]     - __uint_as_float(u0 << 16);
                        const float f1 = x8[2 * p + 1] - __uint_as_float(u1 << 16);
                        const unsigned int v0 = __float_as_uint(f0);
                        const unsigned int v1 = __float_as_uint(f1);
                        const unsigned int l0 = (v0 + 0x7FFFu + ((v0 >> 16) & 1u)) >> 16;
                        const unsigned int l1 = (v1 + 0x7FFFu + ((v1 >> 16) & 1u)) >> 16;
                        hw[p] = u0 | (u1 << 16);
                        lw[p] = l0 | (l1 << 16);
                    }
                    ah = __builtin_bit_cast(bf16x8, (u32x4){hw[0], hw[1], hw[2], hw[3]});
                    al = __builtin_bit_cast(bf16x8, (u32x4){lw[0], lw[1], lw[2], lw[3]});
                }

                #pragma unroll
                for (int n = 0; n < 4; ++n) {
                    acc[n] = __builtin_amdgcn_mfma_f32_16x16x32_bf16(ah, bh[n], acc[n], 0, 0, 0);
                    acc[n] = __builtin_amdgcn_mfma_f32_16x16x32_bf16(ah, bl[n], acc[n], 0, 0, 0);
                    acc[n] = __builtin_amdgcn_mfma_f32_16x16x32_bf16(al, bh[n], acc[n], 0, 0, 0);
                }
            }

            // epilogue: bias (+ReLU) back to LDS (wave-private rows, no barrier)
            #pragma unroll
            for (int n = 0; n < 4; ++n) {
                const float bv = Bsrc[L * DD + n * 16 + lane15];
                #pragma unroll
                for (int r = 0; r < 4; ++r) {
                    float val = acc[n][r] + bv;
                    if (L < 2) val = fmaxf(val, 0.f);
                    hs[(wrow + lhi * 4 + r) * 68 + n * 16 + lane15] = val;
                }
            }
        }

        // write result rows (coalesced)
        #pragma unroll
        for (int rr = 0; rr < 16; ++rr) {
            o[(br * 64 + wrow + rr) * DD + l] = hs[(wrow + rr) * 68 + l];
        }

        // fused 32-row chunk sums (K-mlps only): csum[mc][br*2+hh][d]
        if (q >= 1) {
            __syncthreads();
            const int m = q - 1;
            float p0 = 0.f, p1 = 0.f;
            #pragma unroll
            for (int rr = 0; rr < 16; ++rr) {
                const int row = w * 16 + rr;
                const float kv = hs[row * 68 + l];
                p0 += kv * vb[row];
                p1 += kv * vb[DD + row];
            }
            ps[w][0][l] = p0; ps[w][1][l] = p1;
            __syncthreads();
            const int hh = w >> 1, c = w & 1;
            const float s = ps[2 * hh][c][l] + ps[2 * hh + 1][c][l];
            ws[CSUM_OFF + ((m * 2 + c) * NCH2 + br * 2 + hh) * DD + l] = s;
        }
    }

    __threadfence();
    grid.sync();

    // ---------------- Phase B: zfill (Z inclusive prefix) ----------------
    const int wave_id = b * 4 + w;
    if (wave_id < 8 * NCH2) {
        const int mc  = wave_id >> 7;   // m*2 + c
        const int ch2 = wave_id & 127;
        const int m   = mc >> 1;
        const int c   = mc & 1;
        const int d   = l;
        const float* xm = (m == 0) ? x1 : (m == 1) ? x2 : (m == 2) ? x3 : x4;
        const float* K = ws + K_OFF + m * TT * DD;
        const float* csum = ws + CSUM_OFF + mc * NCH2 * DD;
        float* Z = ws + Z_OFF + mc * TT * DD;

        float r = 0.f;
        #pragma unroll
        for (int cc = 0; cc < NCH2 - 1; ++cc) {
            const float v = csum[cc * DD + d];
            r += (cc < ch2) ? v : 0.f;
        }

        const int j0 = ch2 * CS2;
        #pragma unroll 8
        for (int jj = 0; jj < CS2; ++jj) {
            const int j = j0 + jj;
            r += K[j * DD + d] * xm[j * DD + c];
            Z[j * DD + d] = r;
        }
    }

    __threadfence();
    grid.sync();

    // ---------------- Phase C: gather (output) ----------------
    {
        const float* Q  = ws + Q_OFF;
        const float* Z  = ws + Z_OFF;
        const float* tb = ws + T_OFF;

        for (int i = wave_id; i < TT; i += 1280) {
            const float t1i = tb[i];
            const float qd  = Q[i * DD + l];

            int lo[4] = {0, 0, 0, 0};
            int hi[4] = {TT, TT, TT, TT};
            #pragma unroll
            for (int s = 0; s < 13; ++s) {
                #pragma unroll
                for (int m = 0; m < 4; ++m) {
                    if (lo[m] < hi[m]) {
                        const int mid = (lo[m] + hi[m]) >> 1;
                        const bool le = tb[m * TT + mid] <= t1i;
                        lo[m] = le ? mid + 1 : lo[m];
                        hi[m] = le ? hi[m] : mid;
                    }
                }
            }

            float a0 = 0.f, a1 = 0.f;
            #pragma unroll
            for (int m = 0; m < 4; ++m) {
                if (lo[m] > 0) {
                    const int p = lo[m] - 1;
                    a0 += qd * Z[((m * 2 + 0) * TT + p) * DD + l];
                    a1 += qd * Z[((m * 2 + 1) * TT + p) * DD + l];
                }
            }

            #pragma unroll
            for (int off = 32; off > 0; off >>= 1) {
                a0 += __shfl_xor(a0, off);
                a1 += __shfl_xor(a1, off);
            }
            if (l == 0) {
                out[i * 2 + 0] = a0;
                out[i * 2 + 1] = a1;
            }
        }
    }
}

extern "C" void kernel_launch(void* const* d_in, const int* in_sizes, int n_in,
                              void* d_out, int out_size, void* d_ws, size_t ws_size,
                              hipStream_t stream)
{
    const float* x1   = (const float*)d_in[0];
    const float* x2   = (const float*)d_in[1];
    const float* x3   = (const float*)d_in[2];
    const float* x4   = (const float*)d_in[3];
    const float* Wq_w = (const float*)d_in[4];
    const float* Wq_b = (const float*)d_in[5];
    const float* Wk_w = (const float*)d_in[6];
    const float* Wk_b = (const float*)d_in[7];
    float* out = (float*)d_out;
    float* ws  = (float*)d_ws;

    void* args[] = {(void*)&x1, (void*)&x2, (void*)&x3, (void*)&x4,
                    (void*)&Wq_w, (void*)&Wq_b, (void*)&Wk_w, (void*)&Wk_b,
                    (void*)&ws, (void*)&out};
    hipLaunchCooperativeKernel((const void*)fused_kernel, dim3(320), dim3(256),
                               args, 0, stream);
}

// Round 10
// 48.816 us; speedup vs baseline: 4.6435x; 4.6435x over previous
//
#include <hip/hip_runtime.h>

typedef __attribute__((ext_vector_type(8))) short bf16x8;
typedef __attribute__((ext_vector_type(4))) float f32x4;
typedef __attribute__((ext_vector_type(4))) unsigned int u32x4;

#define TT 4096
#define DD 64
#define NCH2 128
#define CS2 32   // TT / NCH2

// ws layout (in floats)
#define Q_OFF    0
#define K_OFF    (TT*DD)                    // 262144
#define Z_OFF    (K_OFF + 4*TT*DD)          // 1310720
#define CSUM_OFF (Z_OFF + 8*TT*DD)          // 3407872  (8*NCH2*DD = 65536)
#define T_OFF    (CSUM_OFF + 8*NCH2*DD)     // 3473408  (4*TT = 16384) ~13.9 MB

// ---------------------------------------------------------------------------
// Kernel 1: five MLPs via MFMA (split-bf16, hh+hl+lh) with IN-REGISTER W
// fragment conversion (r9 Phase A, validated absmax 0.0625) + fused 32-row
// chunk sums + V/t extraction.  Block = 256 threads (4 waves) per 64-row
// tile; wave w owns rows [16w,16w+16) = one 16x16x32 M-tile; 320 blocks.
// W is 48 KB per mlp -> L2-resident across the 64 blocks sharing it.
// ---------------------------------------------------------------------------
__global__ __launch_bounds__(256) void mlpmm_kernel(
    const float* __restrict__ x1, const float* __restrict__ x2,
    const float* __restrict__ x3, const float* __restrict__ x4,
    const float* __restrict__ Wq_w, const float* __restrict__ Wq_b,
    const float* __restrict__ Wk_w, const float* __restrict__ Wk_b,
    float* __restrict__ ws)
{
    const int tid = threadIdx.x;
    const int l   = tid & 63;
    const int w   = tid >> 6;
    const int q   = blockIdx.x >> 6;   // 0 = Q-mlp, 1..4 = K-mlp (m=q-1)
    const int br  = blockIdx.x & 63;   // 64-row tile

    const float* x; const float* Wsrc; const float* Bsrc; float* o;
    if (q == 0) { x = x1; Wsrc = Wq_w; Bsrc = Wq_b; o = ws + Q_OFF; }
    else {
        const int m = q - 1;
        x = (m == 0) ? x1 : (m == 1) ? x2 : (m == 2) ? x3 : x4;
        Wsrc = Wk_w + m * 3 * DD * DD;
        Bsrc = Wk_b + m * 3 * DD;
        o = ws + K_OFF + m * TT * DD;
    }

    __shared__ float hs[64 * 68];
    __shared__ float vb[2 * 64];
    __shared__ float ps[4][2][64];

    // coalesced tile load: 64x64 = 1024 float4 over 256 threads
    {
        const float4* xv = reinterpret_cast<const float4*>(x + br * 64 * DD);
        #pragma unroll
        for (int i = 0; i < 4; ++i) {
            const int idx = tid + i * 256;
            const float4 v = xv[idx];
            const int e = idx * 4;
            const int row = e >> 6, k0 = e & 63;
            *reinterpret_cast<float4*>(&hs[row * 68 + k0]) = v;
            if (k0 == 0) { vb[row] = v.x; vb[DD + row] = v.y; }
            if (q >= 1 && k0 == 60) ws[T_OFF + (q - 1) * TT + br * 64 + row] = v.w;
        }
    }
    __syncthreads();

    const int lane15 = l & 15, lhi = l >> 4;
    const int wrow = w * 16;

    for (int L = 0; L < 3; ++L) {
        f32x4 acc[4];
        #pragma unroll
        for (int n = 0; n < 4; ++n) acc[n] = (f32x4){0.f, 0.f, 0.f, 0.f};

        #pragma unroll
        for (int t = 0; t < 2; ++t) {
            // B fragments: lane l supplies W[t*32+lhi*8+j][n*16+lane15]
            bf16x8 bh[4], bl[4];
            #pragma unroll
            for (int n = 0; n < 4; ++n) {
                const float* wp0 = Wsrc + L * DD * DD
                                 + (t * 32 + lhi * 8) * DD + n * 16 + lane15;
                unsigned int hw[4], lw[4];
                #pragma unroll
                for (int p = 0; p < 4; ++p) {
                    const float w0 = wp0[(2 * p) * DD];
                    const float w1 = wp0[(2 * p + 1) * DD];
                    const unsigned int u0 = __float_as_uint(w0) >> 16;
                    const unsigned int u1 = __float_as_uint(w1) >> 16;
                    const float f0 = w0 - __uint_as_float(u0 << 16);
                    const float f1 = w1 - __uint_as_float(u1 << 16);
                    const unsigned int v0 = __float_as_uint(f0);
                    const unsigned int v1 = __float_as_uint(f1);
                    const unsigned int l0 = (v0 + 0x7FFFu + ((v0 >> 16) & 1u)) >> 16;
                    const unsigned int l1 = (v1 + 0x7FFFu + ((v1 >> 16) & 1u)) >> 16;
                    hw[p] = u0 | (u1 << 16);
                    lw[p] = l0 | (l1 << 16);
                }
                bh[n] = __builtin_bit_cast(bf16x8, (u32x4){hw[0], hw[1], hw[2], hw[3]});
                bl[n] = __builtin_bit_cast(bf16x8, (u32x4){lw[0], lw[1], lw[2], lw[3]});
            }

            // A fragment from LDS + split conversion
            bf16x8 ah, al;
            {
                const float* src = &hs[(wrow + lane15) * 68 + t * 32 + lhi * 8];
                float x8[8];
                *reinterpret_cast<float4*>(&x8[0]) = *reinterpret_cast<const float4*>(src);
                *reinterpret_cast<float4*>(&x8[4]) = *reinterpret_cast<const float4*>(src + 4);
                unsigned int hw[4], lw[4];
                #pragma unroll
                for (int p = 0; p < 4; ++p) {
                    const unsigned int u0 = __float_as_uint(x8[2 * p]) >> 16;
                    const unsigned int u1 = __float_as_uint(x8[2 * p + 1]) >> 16;
                    const float f0 = x8[2 * p]     - __uint_as_float(u0 << 16);
                    const float f1 = x8[2 * p + 1] - __uint_as_float(u1 << 16);
                    const unsigned int v0 = __float_as_uint(f0);
                    const unsigned int v1 = __float_as_uint(f1);
                    const unsigned int l0 = (v0 + 0x7FFFu + ((v0 >> 16) & 1u)) >> 16;
                    const unsigned int l1 = (v1 + 0x7FFFu + ((v1 >> 16) & 1u)) >> 16;
                    hw[p] = u0 | (u1 << 16);
                    lw[p] = l0 | (l1 << 16);
                }
                ah = __builtin_bit_cast(bf16x8, (u32x4){hw[0], hw[1], hw[2], hw[3]});
                al = __builtin_bit_cast(bf16x8, (u32x4){lw[0], lw[1], lw[2], lw[3]});
            }

            #pragma unroll
            for (int n = 0; n < 4; ++n) {
                acc[n] = __builtin_amdgcn_mfma_f32_16x16x32_bf16(ah, bh[n], acc[n], 0, 0, 0);
                acc[n] = __builtin_amdgcn_mfma_f32_16x16x32_bf16(ah, bl[n], acc[n], 0, 0, 0);
                acc[n] = __builtin_amdgcn_mfma_f32_16x16x32_bf16(al, bh[n], acc[n], 0, 0, 0);
            }
        }

        // epilogue: bias (+ReLU) back to LDS (wave-private rows, no barrier)
        #pragma unroll
        for (int n = 0; n < 4; ++n) {
            const float bv = Bsrc[L * DD + n * 16 + lane15];
            #pragma unroll
            for (int r = 0; r < 4; ++r) {
                float val = acc[n][r] + bv;
                if (L < 2) val = fmaxf(val, 0.f);
                hs[(wrow + lhi * 4 + r) * 68 + n * 16 + lane15] = val;
            }
        }
    }

    // write result rows (coalesced)
    #pragma unroll
    for (int rr = 0; rr < 16; ++rr) {
        o[(br * 64 + wrow + rr) * DD + l] = hs[(wrow + rr) * 68 + l];
    }

    // fused 32-row chunk sums (K-mlps only): csum[mc][br*2+hh][d]
    if (q >= 1) {
        __syncthreads();
        const int m = q - 1;
        float p0 = 0.f, p1 = 0.f;
        #pragma unroll
        for (int rr = 0; rr < 16; ++rr) {
            const int row = w * 16 + rr;
            const float kv = hs[row * 68 + l];
            p0 += kv * vb[row];
            p1 += kv * vb[DD + row];
        }
        ps[w][0][l] = p0; ps[w][1][l] = p1;
        __syncthreads();
        const int hh = w >> 1, c = w & 1;
        const float s = ps[2 * hh][c][l] + ps[2 * hh + 1][c][l];
        ws[CSUM_OFF + ((m * 2 + c) * NCH2 + br * 2 + hh) * DD + l] = s;
    }
}

// ---------------------------------------------------------------------------
// Kernel 2: inclusive prefix Z[mc][j][d], BOTH c columns per wave (halves
// K traffic and wave count vs r8). One wave per (m, ch2); prefix fold is an
// unconditional 2x127-load burst + select; main loop unroll 8.
// ---------------------------------------------------------------------------
__global__ __launch_bounds__(64) void zfill_kernel(
    const float* __restrict__ x1, const float* __restrict__ x2,
    const float* __restrict__ x3, const float* __restrict__ x4,
    float* __restrict__ ws)
{
    const int m   = blockIdx.x >> 7;
    const int ch2 = blockIdx.x & 127;
    const int d   = threadIdx.x;
    const float* xm = (m == 0) ? x1 : (m == 1) ? x2 : (m == 2) ? x3 : x4;
    const float* K = ws + K_OFF + m * TT * DD;
    const float* cs0 = ws + CSUM_OFF + (m * 2 + 0) * NCH2 * DD;
    const float* cs1 = ws + CSUM_OFF + (m * 2 + 1) * NCH2 * DD;
    float* Z0 = ws + Z_OFF + (m * 2 + 0) * TT * DD;
    float* Z1 = ws + Z_OFF + (m * 2 + 1) * TT * DD;

    float r0 = 0.f, r1 = 0.f;
    #pragma unroll
    for (int cc = 0; cc < NCH2 - 1; ++cc) {
        const float v0 = cs0[cc * DD + d];
        const float v1 = cs1[cc * DD + d];
        r0 += (cc < ch2) ? v0 : 0.f;
        r1 += (cc < ch2) ? v1 : 0.f;
    }

    const int j0 = ch2 * CS2;
    #pragma unroll 8
    for (int jj = 0; jj < CS2; ++jj) {
        const int j = j0 + jj;
        const float kv = K[j * DD + d];
        r0 += kv * xm[j * DD + 0];
        r1 += kv * xm[j * DD + 1];
        Z0[j * DD + d] = r0;
        Z1[j * DD + d] = r1;
    }
}

// ---------------------------------------------------------------------------
// Kernel 3: wave-per-row output. 4 binary searches interleaved (independent
// chains) on dense t-arrays, then out_i = Q_i . Z[p-1], 64-lane shuffle
// reduce. (verbatim r3/r8)
// ---------------------------------------------------------------------------
__global__ __launch_bounds__(256) void gather_kernel(
    const float* __restrict__ ws, float* __restrict__ out)
{
    const int lane = threadIdx.x & 63;
    const int wid  = threadIdx.x >> 6;
    const int i = blockIdx.x * 4 + wid;

    const float* Q  = ws + Q_OFF;
    const float* Z  = ws + Z_OFF;
    const float* tb = ws + T_OFF;

    const float t1i = tb[0 * TT + i];
    const float qd  = Q[i * DD + lane];

    int lo[4] = {0, 0, 0, 0};
    int hi[4] = {TT, TT, TT, TT};
    #pragma unroll
    for (int s = 0; s < 13; ++s) {
        #pragma unroll
        for (int m = 0; m < 4; ++m) {
            if (lo[m] < hi[m]) {
                const int mid = (lo[m] + hi[m]) >> 1;
                const bool le = tb[m * TT + mid] <= t1i;
                lo[m] = le ? mid + 1 : lo[m];
                hi[m] = le ? hi[m] : mid;
            }
        }
    }

    float a0 = 0.f, a1 = 0.f;
    #pragma unroll
    for (int m = 0; m < 4; ++m) {
        if (lo[m] > 0) {
            const int p = lo[m] - 1;
            a0 += qd * Z[((m * 2 + 0) * TT + p) * DD + lane];
            a1 += qd * Z[((m * 2 + 1) * TT + p) * DD + lane];
        }
    }

    #pragma unroll
    for (int off = 32; off > 0; off >>= 1) {
        a0 += __shfl_xor(a0, off);
        a1 += __shfl_xor(a1, off);
    }
    if (lane == 0) {
        out[i * 2 + 0] = a0;
        out[i * 2 + 1] = a1;
    }
}

extern "C" void kernel_launch(void* const* d_in, const int* in_sizes, int n_in,
                              void* d_out, int out_size, void* d_ws, size_t ws_size,
                              hipStream_t stream)
{
    const float* x1   = (const float*)d_in[0];
    const float* x2   = (const float*)d_in[1];
    const float* x3   = (const float*)d_in[2];
    const float* x4   = (const float*)d_in[3];
    const float* Wq_w = (const float*)d_in[4];
    const float* Wq_b = (const float*)d_in[5];
    const float* Wk_w = (const float*)d_in[6];
    const float* Wk_b = (const float*)d_in[7];
    float* out = (float*)d_out;
    float* ws  = (float*)d_ws;

    hipLaunchKernelGGL(mlpmm_kernel, dim3(5 * 64), dim3(256), 0, stream,
                       x1, x2, x3, x4, Wq_w, Wq_b, Wk_w, Wk_b, ws);
    hipLaunchKernelGGL(zfill_kernel, dim3(4 * NCH2), dim3(64), 0, stream,
                       x1, x2, x3, x4, ws);
    hipLaunchKernelGGL(gather_kernel, dim3(TT / 4), dim3(256), 0, stream,
                       ws, out);
}

// Round 11
// 42.092 us; speedup vs baseline: 5.3854x; 1.1598x over previous
//
#include <hip/hip_runtime.h>

typedef __attribute__((ext_vector_type(8))) short bf16x8;
typedef __attribute__((ext_vector_type(4))) float f32x4;
typedef __attribute__((ext_vector_type(4))) unsigned int u32x4;

#define TT 4096
#define DD 64
#define NCH2 128
#define CS2 32   // TT / NCH2

// ws layout (in floats)
#define Q_OFF    0
#define K_OFF    (TT*DD)                    // 262144
#define Z_OFF    (K_OFF + 4*TT*DD)          // 1310720
#define CSUM_OFF (Z_OFF + 8*TT*DD)          // 3407872  (8*NCH2*DD = 65536)
#define T_OFF    (CSUM_OFF + 8*NCH2*DD)     // 3473408  (4*TT = 16384)
#define WP_OFF   (T_OFF + 4*TT)             // 3489792  (+61440 floats) ~14.2 MB
#define WP_HALF  61440   // ushorts per precision half (15*2*4*64*8)

// ---------------------------------------------------------------------------
// Kernel 0: pack all 15 layer matrices into MFMA B-fragment layout, bf16
// hi/lo split (hi = truncate, lo = RNE(w - hi)).  Fragment (t,n): lane l
// supplies W[k = t*32+(l>>4)*8+j][c = n*16+(l&15)], j=0..7 contiguous ->
// per-lane 16B, lanes consecutive -> coalesced dwordx4 frag loads in mlpmm.
// ---------------------------------------------------------------------------
__global__ __launch_bounds__(256) void wpack_kernel(
    const float* __restrict__ Wq_w, const float* __restrict__ Wk_w,
    float* __restrict__ ws)
{
    const int ell = blockIdx.x;           // 0..14 = q*3 + L
    const int q = ell / 3, L = ell % 3;
    const float* Wsrc = (q == 0) ? (Wq_w + L * DD * DD)
                                 : (Wk_w + ((q - 1) * 3 + L) * DD * DD);
    unsigned short* wp = reinterpret_cast<unsigned short*>(ws + WP_OFF);
    for (int idx = threadIdx.x; idx < 4096; idx += 256) {
        const int j = idx & 7;
        const int l = (idx >> 3) & 63;
        const int n = (idx >> 9) & 3;
        const int t = (idx >> 11) & 1;
        const int k = t * 32 + (l >> 4) * 8 + j;
        const int c = n * 16 + (l & 15);
        const float wv = Wsrc[k * DD + c];
        const unsigned int u = __float_as_uint(wv);
        const unsigned short hi = (unsigned short)(u >> 16);
        const float hif = __uint_as_float(((unsigned int)hi) << 16);
        const float lof = wv - hif;
        const unsigned int v = __float_as_uint(lof);
        const unsigned short lo = (unsigned short)((v + 0x7FFFu + ((v >> 16) & 1u)) >> 16);
        const int dst = (((ell * 2 + t) * 4 + n) * 64 + l) * 8 + j;
        wp[dst] = hi;
        wp[WP_HALF + dst] = lo;
    }
}

// ---------------------------------------------------------------------------
// Kernel 1: five MLPs via MFMA (split-bf16, 3 terms: hh + hl + lh) + fused
// 32-row chunk sums + V/t extraction.
// Block = 128 threads (2 waves) per 32-row tile; wave w owns rows [16w,16w+16)
// as ONE 16x16x32-mfma M-tile (full 64 output cols = 4 N-tiles, 2 K-tiles).
// W lives in registers as fragments (64 VGPRs hi+lo) -> no per-k weight
// streaming.  h tile in LDS, row stride 68 (16B-aligned b128 reads, bank-
// spread epilogue writes).  No barrier between layers (wave-private rows).
// ---------------------------------------------------------------------------
__global__ __launch_bounds__(128) void mlpmm_kernel(
    const float* __restrict__ x1, const float* __restrict__ x2,
    const float* __restrict__ x3, const float* __restrict__ x4,
    const float* __restrict__ Wq_b, const float* __restrict__ Wk_b,
    float* __restrict__ ws)
{
    const int q   = blockIdx.x >> 7;    // 0 = Q-mlp, 1..4 = K-mlp (m = q-1)
    const int rb  = blockIdx.x & 127;   // 32-row block (= chunk, NCH2=128)
    const int tid = threadIdx.x;
    const int l   = tid & 63;
    const int w   = tid >> 6;           // wave 0..1

    const float* x; const float* Bsrc; float* out;
    if (q == 0) { x = x1; Bsrc = Wq_b; out = ws + Q_OFF; }
    else {
        const int m = q - 1;
        x = (m == 0) ? x1 : (m == 1) ? x2 : (m == 2) ? x3 : x4;
        Bsrc = Wk_b + m * 3 * DD;
        out = ws + K_OFF + m * TT * DD;
    }

    __shared__ float hs[32 * 68];
    __shared__ float vb[2 * 32];
    __shared__ float ps[2][2][64];

    // coalesced tile load: 32 rows x 64 dims = 512 float4
    {
        const float4* xv = reinterpret_cast<const float4*>(x + rb * 32 * DD);
        #pragma unroll
        for (int i = 0; i < 4; ++i) {
            const int idx = tid + i * 128;
            const float4 v = xv[idx];
            const int e = idx * 4;
            const int row = e >> 6, k0 = e & 63;
            *reinterpret_cast<float4*>(&hs[row * 68 + k0]) = v;
            if (k0 == 0) { vb[row] = v.x; vb[32 + row] = v.y; }
            if (q >= 1 && k0 == 60) ws[T_OFF + (q - 1) * TT + rb * 32 + row] = v.w;
        }
    }
    __syncthreads();

    const unsigned short* wp = reinterpret_cast<const unsigned short*>(ws + WP_OFF);
    const int lane15 = l & 15, lhi = l >> 4;
    const int wrow = w * 16;

    for (int L = 0; L < 3; ++L) {
        // B fragments (hi+lo) for this layer: 16 coalesced 16B loads
        bf16x8 bh[2][4], bl[2][4];
        #pragma unroll
        for (int t = 0; t < 2; ++t) {
            #pragma unroll
            for (int n = 0; n < 4; ++n) {
                const int f = ((((q * 3 + L) * 2 + t) * 4 + n) * 64 + l) * 8;
                bh[t][n] = *reinterpret_cast<const bf16x8*>(wp + f);
                bl[t][n] = *reinterpret_cast<const bf16x8*>(wp + WP_HALF + f);
            }
        }

        // A fragments from LDS + split-bf16 conversion
        bf16x8 ah[2], al[2];
        #pragma unroll
        for (int t = 0; t < 2; ++t) {
            const float* src = &hs[(wrow + lane15) * 68 + t * 32 + lhi * 8];
            float x8[8];
            *reinterpret_cast<float4*>(&x8[0]) = *reinterpret_cast<const float4*>(src);
            *reinterpret_cast<float4*>(&x8[4]) = *reinterpret_cast<const float4*>(src + 4);
            unsigned int hw[4], lw[4];
            #pragma unroll
            for (int p = 0; p < 4; ++p) {
                const unsigned int u0 = __float_as_uint(x8[2*p]);
                const unsigned int u1 = __float_as_uint(x8[2*p+1]);
                const unsigned int h0 = u0 >> 16, h1 = u1 >> 16;
                const float f0 = x8[2*p]   - __uint_as_float(h0 << 16);
                const float f1 = x8[2*p+1] - __uint_as_float(h1 << 16);
                const unsigned int v0 = __float_as_uint(f0), v1 = __float_as_uint(f1);
                const unsigned int l0 = (v0 + 0x7FFFu + ((v0 >> 16) & 1u)) >> 16;
                const unsigned int l1 = (v1 + 0x7FFFu + ((v1 >> 16) & 1u)) >> 16;
                hw[p] = h0 | (h1 << 16);
                lw[p] = l0 | (l1 << 16);
            }
            const u32x4 hv = {hw[0], hw[1], hw[2], hw[3]};
            const u32x4 lv = {lw[0], lw[1], lw[2], lw[3]};
            ah[t] = __builtin_bit_cast(bf16x8, hv);
            al[t] = __builtin_bit_cast(bf16x8, lv);
        }

        f32x4 acc[4];
        #pragma unroll
        for (int n = 0; n < 4; ++n) acc[n] = (f32x4){0.f, 0.f, 0.f, 0.f};

        #pragma unroll
        for (int t = 0; t < 2; ++t) {
            #pragma unroll
            for (int n = 0; n < 4; ++n) {
                acc[n] = __builtin_amdgcn_mfma_f32_16x16x32_bf16(ah[t], bh[t][n], acc[n], 0, 0, 0);
                acc[n] = __builtin_amdgcn_mfma_f32_16x16x32_bf16(ah[t], bl[t][n], acc[n], 0, 0, 0);
                acc[n] = __builtin_amdgcn_mfma_f32_16x16x32_bf16(al[t], bh[t][n], acc[n], 0, 0, 0);
            }
        }

        // epilogue: bias (+ReLU), back to LDS (own rows only -> no barrier)
        #pragma unroll
        for (int n = 0; n < 4; ++n) {
            const float bv = Bsrc[L * DD + n * 16 + lane15];
            #pragma unroll
            for (int r = 0; r < 4; ++r) {
                float val = acc[n][r] + bv;
                if (L < 2) val = fmaxf(val, 0.f);
                hs[(wrow + lhi * 4 + r) * 68 + n * 16 + lane15] = val;
            }
        }
    }

    // write result rows (coalesced)
    #pragma unroll
    for (int rr = 0; rr < 16; ++rr) {
        out[(rb * 32 + wrow + rr) * DD + l] = hs[(wrow + rr) * 68 + l];
    }

    // fused 32-row chunk sums (K-mlps only): csum[mc][rb][d]
    if (q >= 1) {
        __syncthreads();
        const int m = q - 1;
        const int d = tid & 63;
        const int g = tid >> 6;     // 0..1
        float p0 = 0.f, p1 = 0.f;
        #pragma unroll
        for (int rr = 0; rr < 16; ++rr) {
            const int row = g * 16 + rr;
            const float kv = hs[row * 68 + d];
            p0 += kv * vb[row];
            p1 += kv * vb[32 + row];
        }
        ps[g][0][d] = p0; ps[g][1][d] = p1;
        __syncthreads();
        const int c = g;
        const float s = ps[0][c][d] + ps[1][c][d];
        ws[CSUM_OFF + ((m * 2 + c) * NCH2 + rb) * DD + d] = s;
    }
}

// ---------------------------------------------------------------------------
// Kernel 2: inclusive prefix Z[mc][j][d]. One wave per (mc, ch2), CS2=32.
// Chunk-prefix fold = one burst of 127 unconditional coalesced loads + select.
// ---------------------------------------------------------------------------
__global__ __launch_bounds__(64) void zfill_kernel(
    const float* __restrict__ x1, const float* __restrict__ x2,
    const float* __restrict__ x3, const float* __restrict__ x4,
    float* __restrict__ ws)
{
    const int mc  = blockIdx.x >> 7;   // m*2 + c
    const int ch2 = blockIdx.x & 127;
    const int m   = mc >> 1;
    const int c   = mc & 1;
    const int d   = threadIdx.x;
    const float* xm = (m == 0) ? x1 : (m == 1) ? x2 : (m == 2) ? x3 : x4;
    const float* K = ws + K_OFF + m * TT * DD;
    const float* csum = ws + CSUM_OFF + mc * NCH2 * DD;
    float* Z = ws + Z_OFF + mc * TT * DD;

    float r = 0.f;
    #pragma unroll
    for (int cc = 0; cc < NCH2 - 1; ++cc) {
        const float v = csum[cc * DD + d];
        r += (cc < ch2) ? v : 0.f;
    }

    const int j0 = ch2 * CS2;
    #pragma unroll 8
    for (int jj = 0; jj < CS2; ++jj) {
        const int j = j0 + jj;
        r += K[j * DD + d] * xm[j * DD + c];
        Z[j * DD + d] = r;
    }
}

// ---------------------------------------------------------------------------
// Kernel 3: wave-per-row output. 4 binary searches interleaved (independent
// chains) on dense t-arrays, then out_i = Q_i . Z[p-1], 64-lane shuffle reduce.
// ---------------------------------------------------------------------------
__global__ __launch_bounds__(256) void gather_kernel(
    const float* __restrict__ ws, float* __restrict__ out)
{
    const int lane = threadIdx.x & 63;
    const int wid  = threadIdx.x >> 6;
    const int i = blockIdx.x * 4 + wid;

    const float* Q  = ws + Q_OFF;
    const float* Z  = ws + Z_OFF;
    const float* tb = ws + T_OFF;

    const float t1i = tb[0 * TT + i];
    const float qd  = Q[i * DD + lane];

    int lo[4] = {0, 0, 0, 0};
    int hi[4] = {TT, TT, TT, TT};
    #pragma unroll
    for (int s = 0; s < 13; ++s) {
        #pragma unroll
        for (int m = 0; m < 4; ++m) {
            if (lo[m] < hi[m]) {
                const int mid = (lo[m] + hi[m]) >> 1;
                const bool le = tb[m * TT + mid] <= t1i;
                lo[m] = le ? mid + 1 : lo[m];
                hi[m] = le ? hi[m] : mid;
            }
        }
    }

    float a0 = 0.f, a1 = 0.f;
    #pragma unroll
    for (int m = 0; m < 4; ++m) {
        if (lo[m] > 0) {
            const int p = lo[m] - 1;
            a0 += qd * Z[((m * 2 + 0) * TT + p) * DD + lane];
            a1 += qd * Z[((m * 2 + 1) * TT + p) * DD + lane];
        }
    }

    #pragma unroll
    for (int off = 32; off > 0; off >>= 1) {
        a0 += __shfl_xor(a0, off);
        a1 += __shfl_xor(a1, off);
    }
    if (lane == 0) {
        out[i * 2 + 0] = a0;
        out[i * 2 + 1] = a1;
    }
}

extern "C" void kernel_launch(void* const* d_in, const int* in_sizes, int n_in,
                              void* d_out, int out_size, void* d_ws, size_t ws_size,
                              hipStream_t stream)
{
    const float* x1   = (const float*)d_in[0];
    const float* x2   = (const float*)d_in[1];
    const float* x3   = (const float*)d_in[2];
    const float* x4   = (const float*)d_in[3];
    const float* Wq_w = (const float*)d_in[4];
    const float* Wq_b = (const float*)d_in[5];
    const float* Wk_w = (const float*)d_in[6];
    const float* Wk_b = (const float*)d_in[7];
    float* out = (float*)d_out;
    float* ws  = (float*)d_ws;

    hipLaunchKernelGGL(wpack_kernel, dim3(15), dim3(256), 0, stream,
                       Wq_w, Wk_w, ws);
    hipLaunchKernelGGL(mlpmm_kernel, dim3(5 * 128), dim3(128), 0, stream,
                       x1, x2, x3, x4, Wq_b, Wk_b, ws);
    hipLaunchKernelGGL(zfill_kernel, dim3(8 * NCH2), dim3(64), 0, stream,
                       x1, x2, x3, x4, ws);
    hipLaunchKernelGGL(gather_kernel, dim3(TT / 4), dim3(256), 0, stream,
                       ws, out);
}